// Round 7
// baseline (200.987 us; speedup 1.0000x reference)
//
#include <hip/hip_runtime.h>
#include <stdint.h>

typedef short short8 __attribute__((ext_vector_type(8)));
typedef float f32x4 __attribute__((ext_vector_type(4)));
typedef float f32x16 __attribute__((ext_vector_type(16)));
typedef unsigned int u32x4 __attribute__((ext_vector_type(4)));
typedef unsigned int u32x2 __attribute__((ext_vector_type(2)));
typedef float float4e __attribute__((ext_vector_type(4)));
typedef unsigned short u16;

#define BB 4
#define SS 2048
#define DD 1024
#define HH 16
#define MM (BB*SS)   // 8192

// ---------- helpers ----------
__device__ __forceinline__ u16 f2bf(float f) {
    unsigned u = __float_as_uint(f);
    u += 0x7FFFu + ((u >> 16) & 1u);   // RTN-even
    return (u16)(u >> 16);
}
__device__ __forceinline__ float bf2f(u16 h) {
    return __uint_as_float(((unsigned)h) << 16);
}
__device__ __forceinline__ unsigned cvtpk(float a, float b) {
    unsigned r;
    asm("v_cvt_pk_bf16_f32 %0, %1, %2" : "=v"(r) : "v"(a), "v"(b));
    return r;
}
// async global->LDS, 16B per lane. dst must be wave-uniform base (HW adds lane*16).
__device__ __forceinline__ void gload16(const void* g, void* l) {
    __builtin_amdgcn_global_load_lds(
        (const __attribute__((address_space(1))) unsigned int*)(uintptr_t)g,
        (__attribute__((address_space(3))) unsigned int*)(unsigned)(uintptr_t)l,
        16, 0, 0);
}
__device__ __forceinline__ bool tens_is_bf(const u16* mref) { return mref[1] == 0xCE6Eu; }

// ---------- kernel 1: x -> bf16 ----------
__global__ __launch_bounds__(256) void cvt_x(const void* xin, u16* xb, const u16* mref) {
    bool isbf = tens_is_bf(mref);
    size_t i = (size_t)blockIdx.x * 256 + threadIdx.x;   // handles 8 elements
    if (isbf) {
        ((u32x4*)xb)[i] = ((const u32x4*)xin)[i];
    } else {
        const float4e* src = (const float4e*)xin;
        float4e a = src[2*i], b = src[2*i+1];
        u32x4 o;
        o[0] = (unsigned)f2bf(a[0]) | ((unsigned)f2bf(a[1]) << 16);
        o[1] = (unsigned)f2bf(a[2]) | ((unsigned)f2bf(a[3]) << 16);
        o[2] = (unsigned)f2bf(b[0]) | ((unsigned)f2bf(b[1]) << 16);
        o[3] = (unsigned)f2bf(b[2]) | ((unsigned)f2bf(b[3]) << 16);
        ((u32x4*)xb)[i] = o;
    }
}

// ---------- kernel 2: weights -> bf16 W^T [N][K] ----------
__global__ __launch_bounds__(256) void trw(const void* w0, const void* w1, const void* w2, const void* w3,
                                           u16* wt, const u16* mref) {
    bool isbf = tens_is_bf(mref);
    const void* w = (blockIdx.z == 0) ? w0 : (blockIdx.z == 1) ? w1 : (blockIdx.z == 2) ? w2 : w3;
    u16* out = wt + (size_t)blockIdx.z * (DD*DD);
    __shared__ float t[32][33];
    int tx = threadIdx.x & 31, ty = threadIdx.x >> 5;    // ty 0..7
    int n0 = blockIdx.x * 32, k0 = blockIdx.y * 32;
#pragma unroll
    for (int i = 0; i < 4; ++i) {
        int k = k0 + ty*4 + i;
        float v = isbf ? bf2f(((const u16*)w)[(size_t)k*DD + n0 + tx])
                       : ((const float*)w)[(size_t)k*DD + n0 + tx];
        t[ty*4 + i][tx] = v;
    }
    __syncthreads();
#pragma unroll
    for (int i = 0; i < 4; ++i)
        out[(size_t)(n0 + ty*4 + i)*DD + k0 + tx] = f2bf(t[tx][ty*4 + i]);
}

#define QSCALE 0.1803368801111204f   // 0.125 * log2(e)

// ---------- kernel 3: fused QKV GEMM, 256x256 tile, BK=64, 8 waves, 8-phase-style schedule ----------
// A[M][K] bf16, Bt[3072][K] bf16 (wq^T|wk^T|wv^T). Grid dim3(32,12).
// Epilogue: n-panel 0-3 -> RoPE*QSCALE -> Q[B,H,S,HD]; 4-7 -> RoPE -> K; 8-11 -> V^T[B,H,64,S] direct stores.
__global__ __launch_bounds__(512, 2) void qkv256(const u16* __restrict__ A, const u16* __restrict__ Bt,
                                                 u16* __restrict__ outQ, u16* __restrict__ outK,
                                                 u16* __restrict__ outVT,
                                                 const void* fcos, const void* fsin) {
    __shared__ __align__(16) u16 Al[2][256*64];   // 64KB
    __shared__ __align__(16) u16 Bl[2][256*64];   // 64KB
    int tid = threadIdx.x;
    int w = tid >> 6, l = tid & 63, lo = l & 15, hi = l >> 4;
    int wr = w >> 2, wc = w & 3;
    int m0 = blockIdx.x * 256, n0 = blockIdx.y * 256;

    f32x4 acc[8][4] = {};

    // stage one half-tile (128 rows x 64 cols) of A or B into buf; rows h*128..
    auto stageA = [&](int buf, int t, int h) {
        const char* src = (const char*)(A + ((size_t)(m0 + h*128) * DD + t*64));
        char* dst = (char*)Al[buf] + h*128*128;
#pragma unroll
        for (int i = 0; i < 2; ++i) {
            int idx = i*512 + tid;
            int row = idx >> 3, inb = (idx & 7) * 16;
            int sw = inb ^ ((row & 7) << 4);
            gload16(src + (size_t)row*(DD*2) + sw, dst + (i*512 + (tid & ~63))*16);
        }
    };
    auto stageB = [&](int buf, int t, int h) {
        const char* src = (const char*)(Bt + ((size_t)(n0 + h*128) * DD + t*64));
        char* dst = (char*)Bl[buf] + h*128*128;
#pragma unroll
        for (int i = 0; i < 2; ++i) {
            int idx = i*512 + tid;
            int row = idx >> 3, inb = (idx & 7) * 16;
            int sw = inb ^ ((row & 7) << 4);
            gload16(src + (size_t)row*(DD*2) + sw, dst + (i*512 + (tid & ~63))*16);
        }
    };

    const int NT = DD / 64;   // 16
    // prologue: stage K-tile 0 fully
    stageA(0, 0, 0); stageB(0, 0, 0);
    stageA(0, 0, 1); stageB(0, 0, 1);
    asm volatile("s_waitcnt vmcnt(0)" ::: "memory");
    __builtin_amdgcn_s_barrier();

    for (int t = 0; t < NT; ++t) {
        int buf = t & 1, nbuf = buf ^ 1;
        bool pre = (t + 1 < NT);
        const char* Ab = (const char*)Al[buf];
        const char* Bb = (const char*)Bl[buf];

        short8 bfr[4][2];   // B frags: ni x ksub, loaded once per K-tile (phase 0)

        // ---- 4 phases: phase j computes mi = {2j, 2j+1} x ni 0..3 x ksub 0..1 (16 MFMA) ----
#pragma unroll
        for (int j = 0; j < 4; ++j) {
            // stage next K-tile's half-tiles during phases 0/1
            if (j == 0 && pre) { stageA(nbuf, t+1, 0); stageB(nbuf, t+1, 0); }
            if (j == 1 && pre) { stageA(nbuf, t+1, 1); stageB(nbuf, t+1, 1); }
            // B frags (phase 0 only)
            if (j == 0) {
#pragma unroll
                for (int ni = 0; ni < 4; ++ni) {
                    int lrow = wc*64 + ni*16 + lo;
#pragma unroll
                    for (int ks = 0; ks < 2; ++ks)
                        bfr[ni][ks] = *(const short8*)(Bb + lrow*128 + ((ks*64 + hi*16) ^ ((lrow & 7) << 4)));
                }
            }
            // A frags for this phase
            short8 af[2][2];
#pragma unroll
            for (int mm = 0; mm < 2; ++mm) {
                int lrow = wr*128 + (2*j + mm)*16 + lo;
#pragma unroll
                for (int ks = 0; ks < 2; ++ks)
                    af[mm][ks] = *(const short8*)(Ab + lrow*128 + ((ks*64 + hi*16) ^ ((lrow & 7) << 4)));
            }
            __builtin_amdgcn_s_barrier();
            __builtin_amdgcn_s_setprio(1);
#pragma unroll
            for (int ks = 0; ks < 2; ++ks)
#pragma unroll
                for (int mm = 0; mm < 2; ++mm)
#pragma unroll
                    for (int ni = 0; ni < 4; ++ni)
                        acc[2*j + mm][ni] = __builtin_amdgcn_mfma_f32_16x16x32_bf16(af[mm][ks], bfr[ni][ks], acc[2*j + mm][ni], 0, 0, 0);
            __builtin_amdgcn_s_setprio(0);
            if (j == 3) {
                if (pre) asm volatile("s_waitcnt vmcnt(0)" ::: "memory");   // next tile fully landed (issued >=2 phases ago)
            }
            __builtin_amdgcn_s_barrier();
        }
    }

    // ---- epilogue ----
    int wi = n0 >> 10;          // 0 Q, 1 K, 2 V
    int n0w = n0 & 1023;
    if (wi == 2) {
        // V: direct transposed stores, 8B per (mi,ni) per lane
        int gc = n0w + wc*64;   // base col
#pragma unroll
        for (int ni = 0; ni < 4; ++ni) {
            int col = gc + ni*16 + lo;
            int d = col & 63, h = col >> 6;
#pragma unroll
            for (int mi = 0; mi < 8; ++mi) {
                int srow = m0 + wr*128 + mi*16 + hi*4;
                int b = srow >> 11, s0 = srow & (SS-1);
                u32x2 pk;
                pk[0] = cvtpk(acc[mi][ni][0], acc[mi][ni][1]);
                pk[1] = cvtpk(acc[mi][ni][2], acc[mi][ni][3]);
                *(u32x2*)(outVT + ((size_t)(b*HH + h)*64 + d)*SS + s0) = pk;
            }
        }
    } else {
        bool fbf = (((const u16*)fcos)[0] == 0x3F80u);
        u16* outp = wi ? outK : outQ;
        float oscale = wi ? 1.0f : QSCALE;
#pragma unroll
        for (int mi = 0; mi < 8; ++mi)
#pragma unroll
            for (int ni = 0; ni < 4; ++ni)
#pragma unroll
                for (int r = 0; r < 4; ++r) {
                    int gm = m0 + wr*128 + mi*16 + hi*4 + r;
                    int gc = n0w + wc*64 + ni*16 + lo;
                    float v  = acc[mi][ni][r];
                    float vp = __shfl_xor(v, 1);
                    int s = gm & (SS-1), d = gc & 63, i2 = d >> 1;
                    float co, sn;
                    if (fbf) { co = bf2f(((const u16*)fcos)[s*32 + i2]); sn = bf2f(((const u16*)fsin)[s*32 + i2]); }
                    else     { co = ((const float*)fcos)[s*32 + i2];     sn = ((const float*)fsin)[s*32 + i2]; }
                    float o = (gc & 1) ? (vp*sn + v*co) : (v*co - vp*sn);
                    o *= oscale;
                    int b = gm >> 11, h = gc >> 6;
                    outp[((((size_t)b*HH + h)*SS + s) << 6) + d] = f2bf(o);
                }
    }
}

// ---------- kernel 3b: final projection, 128x128 tile (proven R3 config) ----------
__global__ __launch_bounds__(256) void proj128(const u16* __restrict__ A, const u16* __restrict__ Bt,
                                               void* Cout, const u16* mref) {
    __shared__ __align__(16) unsigned char smem[32768];
    int tid = threadIdx.x;
    int w = tid >> 6, l = tid & 63, lo = l & 15, hi = l >> 4;
    int wm = w >> 1, wn = w & 1;
    int m0 = blockIdx.x * 128, n0 = blockIdx.y * 128;

    f32x4 acc[4][4] = {};

    auto stage = [&](int buf, int t) {
        int k0 = t * 32;
#pragma unroll
        for (int i = 0; i < 2; ++i) {
            int o = (i*256 + tid) * 16;
            int row = o >> 6, inb = o & 63;
            int sw  = inb ^ ((row & 3) << 4);
            gload16((const char*)A + ((size_t)(m0 + row)*DD + k0)*2 + sw,
                    smem + buf*16384 + (i*256 + (tid & ~63))*16);
            gload16((const char*)Bt + ((size_t)(n0 + row)*DD + k0)*2 + sw,
                    smem + buf*16384 + 8192 + (i*256 + (tid & ~63))*16);
        }
    };

    stage(0, 0);
    __syncthreads();
    int cur = 0;
    const int NT = DD / 32;
    for (int t = 0; t < NT; ++t) {
        if (t + 1 < NT) stage(cur ^ 1, t + 1);
        const char* Ab = (const char*)(smem + cur*16384);
        const char* Bb = Ab + 8192;
        short8 af[4], bfr[4];
#pragma unroll
        for (int mi = 0; mi < 4; ++mi) {
            int r = wm*64 + mi*16 + lo;
            af[mi] = *(const short8*)(Ab + r*64 + ((hi*16) ^ ((r & 3) << 4)));
        }
#pragma unroll
        for (int ni = 0; ni < 4; ++ni) {
            int r = wn*64 + ni*16 + lo;
            bfr[ni] = *(const short8*)(Bb + r*64 + ((hi*16) ^ ((r & 3) << 4)));
        }
        __builtin_amdgcn_s_setprio(1);
#pragma unroll
        for (int mi = 0; mi < 4; ++mi)
#pragma unroll
            for (int ni = 0; ni < 4; ++ni)
                acc[mi][ni] = __builtin_amdgcn_mfma_f32_16x16x32_bf16(af[mi], bfr[ni], acc[mi][ni], 0, 0, 0);
        __builtin_amdgcn_s_setprio(0);
        __syncthreads();
        cur ^= 1;
    }

    bool isbf = tens_is_bf(mref);
#pragma unroll
    for (int mi = 0; mi < 4; ++mi)
#pragma unroll
        for (int ni = 0; ni < 4; ++ni)
#pragma unroll
            for (int r = 0; r < 4; ++r) {
                int gm = m0 + wm*64 + mi*16 + hi*4 + r;
                int gc = n0 + wn*64 + ni*16 + lo;
                float v = acc[mi][ni][r];
                if (isbf) ((u16*)Cout)[(size_t)gm*DD + gc] = f2bf(v);
                else      ((float*)Cout)[(size_t)gm*DD + gc] = v;
            }
}

// ---------- kernel 4: causal flash attention v6 (unchanged from R6, measured best) ----------
__global__ __launch_bounds__(256) void attn(const u16* __restrict__ Q, const u16* __restrict__ K,
                                            const u16* __restrict__ VT, u16* __restrict__ AO) {
    __shared__ __align__(16) u16 Kl[2][64*64];
    __shared__ __align__(16) u16 Vl[2][64*64];
    int bh = blockIdx.x;
    int qt = (gridDim.y - 1) - blockIdx.y;          // longest first
    int tid = threadIdx.x, w = tid >> 6, l = tid & 63;
    int l31 = l & 31, hi5 = l >> 5;
    const u16* Qb = Q  + (size_t)bh * SS * 64;
    const u16* Kb = K  + (size_t)bh * SS * 64;
    const u16* Vb = VT + (size_t)bh * 64 * SS;
    int q0w = qt*128 + w*32;
    int q   = q0w + l31;

    short8 qf[4];
#pragma unroll
    for (int kc = 0; kc < 4; ++kc)
        qf[kc] = *(const short8*)(Qb + (size_t)q*64 + kc*16 + hi5*8);

    int loff[2][4];
#pragma unroll
    for (int g = 0; g < 2; ++g)
#pragma unroll
        for (int kc = 0; kc < 4; ++kc) {
            int row = g*32 + l31;
            int ib = kc*32 + hi5*16;
            loff[g][kc] = row*128 + (ib ^ ((row & 7) << 4));
        }

    f32x16 oacc[2] = {};
    float m_ = -1e30f, l_ = 0.f;

    auto stage = [&](int buf, int kt) {
        const char* Kt = (const char*)(Kb + (size_t)kt*64*64);
        const char* Vt = (const char*)Vb + (size_t)kt*128;
#pragma unroll
        for (int i = 0; i < 2; ++i) {
            int idx = i*256 + tid;
            int row = idx >> 3, inb = (idx & 7) * 16;
            int sw = inb ^ ((row & 7) << 4);
            gload16(Kt + row*128 + sw,            (char*)Kl[buf] + (i*256 + (tid & ~63))*16);
            gload16(Vt + (size_t)row*(SS*2) + sw, (char*)Vl[buf] + (i*256 + (tid & ~63))*16);
        }
    };

    int nkt = 2*qt + 2;
    stage(0, 0);
    __syncthreads();
    int cur = 0;

    for (int kt = 0; kt < nkt; ++kt) {
        if (kt + 1 < nkt) stage(cur ^ 1, kt + 1);

        if (kt*64 <= q0w + 31) {
            const char* Kc = (const char*)Kl[cur];
            const char* Vc = (const char*)Vl[cur];
            f32x16 sc[2] = {};
            __builtin_amdgcn_s_setprio(1);
#pragma unroll
            for (int kvt = 0; kvt < 2; ++kvt) {
                short8 kf[4];
#pragma unroll
                for (int kc = 0; kc < 4; ++kc)
                    kf[kc] = *(const short8*)(Kc + loff[kvt][kc]);
#pragma unroll
                for (int kc = 0; kc < 4; ++kc)
                    sc[kvt] = __builtin_amdgcn_mfma_f32_32x32x16_bf16(kf[kc], qf[kc], sc[kvt], 0, 0, 0);
            }
            __builtin_amdgcn_s_setprio(0);

            if (kt*64 + 63 > q0w) {
#pragma unroll
                for (int kvt = 0; kvt < 2; ++kvt)
#pragma unroll
                    for (int rg = 0; rg < 16; ++rg) {
                        int kv = kt*64 + kvt*32 + (rg & 3) + 8*(rg >> 2) + 4*hi5;
                        if (kv > q) sc[kvt][rg] = -1e9f;
                    }
            }

            float m8[8];
#pragma unroll
            for (int j = 0; j < 8; ++j)
                m8[j] = fmaxf(fmaxf(sc[0][j], sc[0][j+8]), fmaxf(sc[1][j], sc[1][j+8]));
            float mx = fmaxf(fmaxf(fmaxf(m8[0], m8[1]), fmaxf(m8[2], m8[3])),
                             fmaxf(fmaxf(m8[4], m8[5]), fmaxf(m8[6], m8[7])));
            mx = fmaxf(mx, __shfl_xor(mx, 32));
            if (!__all(mx <= m_ + 8.f)) {
                float mn = fmaxf(m_, mx);
                float al = exp2f(m_ - mn);
                m_ = mn;
                l_ *= al;
#pragma unroll
                for (int dt = 0; dt < 2; ++dt)
#pragma unroll
                    for (int rg = 0; rg < 16; ++rg) oacc[dt][rg] *= al;
            }
#pragma unroll
            for (int kvt = 0; kvt < 2; ++kvt)
#pragma unroll
                for (int rg = 0; rg < 16; ++rg)
                    sc[kvt][rg] = exp2f(sc[kvt][rg] - m_);
            float s8[8];
#pragma unroll
            for (int j = 0; j < 8; ++j)
                s8[j] = (sc[0][j] + sc[0][j+8]) + (sc[1][j] + sc[1][j+8]);
            float rs = ((s8[0] + s8[1]) + (s8[2] + s8[3])) + ((s8[4] + s8[5]) + (s8[6] + s8[7]));
            rs += __shfl_xor(rs, 32);
            l_ += rs;

            short8 pa[4];
#pragma unroll
            for (int kc = 0; kc < 4; ++kc) {
                const int kvt = kc >> 1;
                const int base = (kc & 1) * 8;
                unsigned A0 = cvtpk(sc[kvt][base + 0], sc[kvt][base + 1]);
                unsigned A1 = cvtpk(sc[kvt][base + 2], sc[kvt][base + 3]);
                unsigned B0 = cvtpk(sc[kvt][base + 4], sc[kvt][base + 5]);
                unsigned B1 = cvtpk(sc[kvt][base + 6], sc[kvt][base + 7]);
                asm("v_permlane32_swap_b32 %0, %1" : "+v"(A0), "+v"(B0));
                asm("v_permlane32_swap_b32 %0, %1" : "+v"(A1), "+v"(B1));
                u32x4 pk; pk[0] = A0; pk[1] = A1; pk[2] = B0; pk[3] = B1;
                pa[kc] = __builtin_bit_cast(short8, pk);
            }

            __builtin_amdgcn_s_setprio(1);
#pragma unroll
            for (int dt = 0; dt < 2; ++dt) {
                short8 vf[4];
#pragma unroll
                for (int kc = 0; kc < 4; ++kc)
                    vf[kc] = *(const short8*)(Vc + loff[dt][kc]);
#pragma unroll
                for (int kc = 0; kc < 4; ++kc)
                    oacc[dt] = __builtin_amdgcn_mfma_f32_32x32x16_bf16(vf[kc], pa[kc], oacc[dt], 0, 0, 0);
            }
            __builtin_amdgcn_s_setprio(0);
        }

        __syncthreads();
        cur ^= 1;
    }

    int b = bh >> 4, h = bh & 15;
    float inv = 1.0f / l_;
    u16* aor = AO + (size_t)(b*SS + q)*DD + h*64;
#pragma unroll
    for (int dt = 0; dt < 2; ++dt)
#pragma unroll
        for (int j = 0; j < 8; ++j) {
            int r0 = 2*j, r1 = 2*j + 1;
            int d = dt*32 + (r0 & 3) + 8*(r0 >> 2) + 4*hi5;
            unsigned pk = (unsigned)f2bf(oacc[dt][r0] * inv) | ((unsigned)f2bf(oacc[dt][r1] * inv) << 16);
            *(unsigned*)(aor + d) = pk;
        }
}

// ---------- launch ----------
extern "C" void kernel_launch(void* const* d_in, const int* in_sizes, int n_in,
                              void* d_out, int out_size, void* d_ws, size_t ws_size,
                              hipStream_t stream) {
    const void* x    = d_in[0];
    const void* fcos = d_in[1];
    const void* fsin = d_in[2];
    const u16*  mref = (const u16*)d_in[3];
    const void* wq   = d_in[4];
    const void* wk   = d_in[5];
    const void* wv   = d_in[6];
    const void* wo   = d_in[7];

    u16* ws = (u16*)d_ws;
    const size_t XB = (size_t)MM * DD;     // 8,388,608
    const size_t WT = (size_t)DD * DD;     // 1,048,576
    u16* xb  = ws;                 // x bf16 ; later aliased as attention output
    u16* wt  = ws + XB;            // 4 transposed weights (wq,wk,wv,wo contiguous)
    u16* qb  = ws + XB + 4*WT;
    u16* kb  = qb + XB;
    u16* vtb = kb + XB;

    cvt_x<<<4096, 256, 0, stream>>>(x, xb, mref);
    trw<<<dim3(32, 32, 4), 256, 0, stream>>>(wq, wk, wv, wo, wt, mref);
    // fused QKV: 256x256 tile, 8-phase schedule, 384 blocks
    qkv256<<<dim3(32, 12), 512, 0, stream>>>(xb, wt, qb, kb, vtb, fcos, fsin);
    attn<<<dim3(64, 16), 256, 0, stream>>>(qb, kb, vtb, xb);   // AO aliases xb (safe: stream-ordered)
    proj128<<<dim3(64, 8), 256, 0, stream>>>(xb, wt + 3*WT, d_out, mref);
}